// Round 5
// baseline (486.389 us; speedup 1.0000x reference)
//
#include <hip/hip_runtime.h>
#include <math.h>

#define GROUPS 32
#define CG 16
#define HH 56
#define WW 56
#define HW (HH*WW)          // 3136
#define BG 1024             // B*GROUPS
#define EPS 1e-5f

#define RB 4                // output rows per band
#define NB 14               // bands per instance (RB*NB == HH)
#define NR (RB+2)           // staged rows incl. halo = 6
#define LROW 60             // LDS row stride: [0..3] zero halo, [4..59] image
#define CPAD 4              // zero tail pad per channel (right-edge overread)
#define CSTR (NR*LROW+CPAD) // 364 floats per channel; 364%32=12 -> bank spread
#define XWS 60              // s_xw stride; 60%32=28 -> bank spread
#define GHS 9               // s_gh stride; 9c distinct banks for c=0..15

// ---------------------------------------------------------------------------
// Kernel A (unchanged from R4): fused directional pooling -> 1x1 mix ->
// gates; analytic x2sum; per-channel sum/sumsq; a2-softmax folded.
// ---------------------------------------------------------------------------
__global__ __launch_bounds__(256) void kA(const float* __restrict__ x,
        const float* __restrict__ w1, const float* __restrict__ b1,
        const float* __restrict__ w3, const float* __restrict__ b3,
        const float* __restrict__ gn_w, const float* __restrict__ gn_b,
        float* __restrict__ ws_xh, float* __restrict__ ws_xw,
        float* __restrict__ ws_asc, float* __restrict__ ws_aofs,
        float* __restrict__ ws_wa)
{
    const int g = blockIdx.x;
    const int tid = threadIdx.x;
    const float* gx = x + (size_t)g * CG * HW;

    __shared__ float s_row[CG][HH];
    __shared__ float s_col[CG][WW];
    __shared__ float s_xh[CG][HH];
    __shared__ float s_xw[CG][WW];
    __shared__ float s_st[CG][9];
    __shared__ float s_x2p[CG][CG];
    __shared__ float ls1[CG], ls2[CG];

    if (g == 0 && tid < CG * 9 + 1) {
        float m = gn_b[0];
        #pragma unroll
        for (int c = 1; c < CG; ++c) m = fmaxf(m, gn_b[c]);
        float a1[CG]; float den = 0.f;
        #pragma unroll
        for (int c = 0; c < CG; ++c) { a1[c] = __expf(gn_b[c] - m); den += a1[c]; }
        float inv = 1.f / den;
        if (tid < CG * 9) {
            int ci = tid / 9, k = tid - (tid / 9) * 9;
            float s = 0.f;
            #pragma unroll
            for (int o = 0; o < CG; ++o) s += a1[o] * w3[(size_t)(o * CG + ci) * 9 + k];
            ws_wa[tid] = s * inv;
        } else {
            float s = 0.f;
            #pragma unroll
            for (int o = 0; o < CG; ++o) s += a1[o] * b3[o];
            ws_wa[CG * 9] = s * inv;
        }
    }

    {
        const int grp = tid >> 4;
        const int q   = tid & 15;
        const float* pc = gx + grp * HW;
        float c0 = 0.f, c1 = 0.f, c2 = 0.f, c3 = 0.f;
        #pragma unroll 4
        for (int row = 0; row < HH; ++row) {
            float4 v = make_float4(0.f, 0.f, 0.f, 0.f);
            if (q < 14) v = *(const float4*)(pc + row * WW + q * 4);
            c0 += v.x; c1 += v.y; c2 += v.z; c3 += v.w;
            float rs = (v.x + v.y) + (v.z + v.w);
            rs += __shfl_down(rs, 8);
            rs += __shfl_down(rs, 4);
            rs += __shfl_down(rs, 2);
            rs += __shfl_down(rs, 1);
            if (q == 0) s_row[grp][row] = rs * (1.0f / WW);
        }
        if (q < 14) {
            s_col[grp][q * 4 + 0] = c0 * (1.0f / HH);
            s_col[grp][q * 4 + 1] = c1 * (1.0f / HH);
            s_col[grp][q * 4 + 2] = c2 * (1.0f / HH);
            s_col[grp][q * 4 + 3] = c3 * (1.0f / HH);
        }
    }
    __syncthreads();

    for (int t = tid; t < 2 * CG * HH; t += 256) {
        int hpart = (t < CG * HH);
        int tt = hpart ? t : t - CG * HH;
        int o = tt / HH, i = tt - (tt / HH) * HH;
        float v = b1[o];
        #pragma unroll
        for (int c = 0; c < CG; ++c)
            v += w1[o * CG + c] * (hpart ? s_row[c][i] : s_col[c][i]);
        float sg = 1.f / (1.f + __expf(-v));
        if (hpart) { s_xh[o][i] = sg; ws_xh[(size_t)g * CG * HH + tt] = sg; }
        else       { s_xw[o][i] = sg; ws_xw[(size_t)g * CG * WW + tt] = sg; }
    }

    if (tid < CG) {
        const int c = tid;
        float S = 0.f;
        #pragma unroll
        for (int r = 0; r < HH; ++r) S += s_row[c][r];
        s_st[c][0] = S * (float)WW;
        s_st[c][1] = (float)WW * s_row[c][HH - 1];
        s_st[c][2] = (float)WW * s_row[c][0];
        s_st[c][3] = (float)HH * s_col[c][WW - 1];
        s_st[c][4] = (float)HH * s_col[c][0];
        const float* p = gx + c * HW;
        s_st[c][5] = p[0];
        s_st[c][6] = p[WW - 1];
        s_st[c][7] = p[(HH - 1) * WW];
        s_st[c][8] = p[(HH - 1) * WW + WW - 1];
    }
    __syncthreads();

    {
        const int o = tid >> 4, c = tid & 15;
        const float* wp = w3 + (size_t)(o * CG + c) * 9;
        const float* st = s_st[c];
        float S = st[0];
        float acc = 0.f;
        #pragma unroll
        for (int dy = 0; dy < 3; ++dy) {
            float Rv = (dy == 0) ? st[1] : (dy == 2 ? st[2] : 0.f);
            #pragma unroll
            for (int dx = 0; dx < 3; ++dx) {
                float Cv = (dx == 0) ? st[3] : (dx == 2 ? st[4] : 0.f);
                float T = S - Rv - Cv;
                if (dy != 1 && dx != 1)
                    T += (dy == 0) ? ((dx == 0) ? st[8] : st[7])
                                   : ((dx == 0) ? st[6] : st[5]);
                acc += wp[dy * 3 + dx] * T;
            }
        }
        s_x2p[c][o] = acc;
    }

    {
        const int c = tid >> 4;
        const int q = tid & 15;
        float s1 = 0.f, s2 = 0.f;
        if (q < 14) {
            const float* pc = gx + c * HW;
            float xw0 = s_xw[c][q * 4 + 0], xw1 = s_xw[c][q * 4 + 1];
            float xw2 = s_xw[c][q * 4 + 2], xw3v = s_xw[c][q * 4 + 3];
            #pragma unroll 4
            for (int row = 0; row < HH; ++row) {
                float4 v = *(const float4*)(pc + row * WW + q * 4);
                float xh = s_xh[c][row];
                float t0 = v.x * xh * xw0;
                float t1 = v.y * xh * xw1;
                float t2 = v.z * xh * xw2;
                float t3 = v.w * xh * xw3v;
                s1 += (t0 + t1) + (t2 + t3);
                s2 += (t0 * t0 + t1 * t1) + (t2 * t2 + t3 * t3);
            }
        }
        s1 += __shfl_down(s1, 8);  s2 += __shfl_down(s2, 8);
        s1 += __shfl_down(s1, 4);  s2 += __shfl_down(s2, 4);
        s1 += __shfl_down(s1, 2);  s2 += __shfl_down(s2, 2);
        s1 += __shfl_down(s1, 1);  s2 += __shfl_down(s2, 1);
        if (q == 0) { ls1[c] = s1; ls2[c] = s2; }
    }
    __syncthreads();

    if (tid < CG) {
        const int o = tid;
        float x2 = (float)HW * b3[o];
        #pragma unroll
        for (int c = 0; c < CG; ++c) x2 += s_x2p[c][o];

        float mu  = ls1[o] * (1.0f / HW);
        float var = ls2[o] * (1.0f / HW) - mu * mu;
        float sc  = gn_w[o] * rsqrtf(var + EPS);
        float sh  = gn_b[o] - mu * sc;

        float v2 = x2 * (1.0f / HW);
        float m = v2;
        #pragma unroll
        for (int off = 8; off; off >>= 1) m = fmaxf(m, __shfl_xor(m, off));
        float e = __expf(v2 - m);
        float den = e;
        #pragma unroll
        for (int off = 8; off; off >>= 1) den += __shfl_xor(den, off);
        float a2 = e / den;

        ws_asc[(size_t)g * CG + o] = a2 * sc;
        float part = a2 * sh;
        #pragma unroll
        for (int off = 8; off; off >>= 1) part += __shfl_xor(part, off);
        if (o == 0) ws_aofs[g] = part;
    }
}

// ---------------------------------------------------------------------------
// Kernel BC v3: one block per (instance, 4-row band). Phase 2 task =
// (channel c = tid&15, strip sp = tid>>4): 2 output rows x 8 px for ONE
// channel, reading 4 staged rows x 4 aligned b128 (full window; zero pads
// absorb overreads -> no scalar edge reads). 16-channel reduction is a
// 4-level __shfl_xor butterfly (no s_part, no phase 3, one barrier fewer).
// CSTR=364 / XWS=60 chosen so every wave's b128 lanes spread uniformly
// 8-per-4-bank-slot (conflict-free by enumeration).
// ---------------------------------------------------------------------------
__global__ __launch_bounds__(256, 4) void kBC(const float* __restrict__ x,
        const float* __restrict__ ws_xh, const float* __restrict__ ws_xw,
        const float* __restrict__ ws_asc, const float* __restrict__ ws_aofs,
        const float* __restrict__ ws_wa, float* __restrict__ out)
{
    const int g = blockIdx.x / NB;
    const int band = blockIdx.x - g * NB;
    const int y0 = band * RB;
    const int tid = threadIdx.x;
    const float* gx = x + (size_t)g * CG * HW;
    float* og = out + (size_t)g * CG * HW;

    __shared__ float s_in[CG * CSTR];   // 23296 B
    __shared__ float s_xw[CG * XWS];    //  3840 B
    __shared__ float s_gh[CG * GHS];    //   576 B
    __shared__ float s_wa[CG * 9];      //   576 B
    __shared__ float s_bias;

    // phase 0: zero halos/pads, stage small per-instance data
    if (tid < 96) {                       // left halo cols [0..3] per (c,row)
        int c = tid / NR, r = tid - c * NR;
        *(float4*)&s_in[c * CSTR + r * LROW] = make_float4(0.f, 0.f, 0.f, 0.f);
    } else if (tid < 112) {               // channel tail pad [360..363]
        int c = tid - 96;
        *(float4*)&s_in[c * CSTR + NR * LROW] = make_float4(0.f, 0.f, 0.f, 0.f);
    } else {                              // tid 112..255 -> 144 wa entries
        s_wa[tid - 112] = ws_wa[tid - 112];
    }
    if (tid < CG * 14) {                  // s_xw, padded stride 60
        int c = tid / 14, q = tid - c * 14;
        *(float4*)&s_xw[c * XWS + 4 * q] =
            *(const float4*)&ws_xw[(size_t)g * CG * WW + c * WW + 4 * q];
    }
    if (tid < CG * RB) {                  // s_gh, stride 9
        int c = tid >> 2, r = tid & 3;
        s_gh[c * GHS + r] = ws_asc[(size_t)g * CG + c]
                          * ws_xh[(size_t)g * CG * HH + c * HH + y0 + r];
    }
    if (tid == 255) s_bias = ws_wa[CG * 9] + ws_aofs[0 + g];

    // phase 1: stage rows y0-1 .. y0+RB (zeros for out-of-image rows)
    for (int t = tid; t < CG * NR * (WW / 4); t += 256) {   // 1344
        int c = t / (NR * 14);
        int rem = t - c * (NR * 14);
        int r = rem / 14, q = rem - r * 14;
        int ry = y0 - 1 + r;
        float4 v = make_float4(0.f, 0.f, 0.f, 0.f);
        if (ry >= 0 && ry < HH)
            v = *(const float4*)(gx + c * HW + ry * WW + 4 * q);
        *(float4*)&s_in[c * CSTR + r * LROW + 4 + 4 * q] = v;
    }
    __syncthreads();

    // phase 2: conv + gate + butterfly + epilogue, no further barriers
    if (tid < 224) {
        const int c   = tid & 15;
        const int sp  = tid >> 4;          // 0..13
        const int ypr = sp / 7;            // 0..1
        const int k   = sp - ypr * 7;      // 0..6
        const int x0  = 8 * k;

        float w[9];
        #pragma unroll
        for (int i = 0; i < 9; ++i) w[i] = s_wa[c * 9 + i];

        float4 X0 = *(const float4*)&s_xw[c * XWS + x0];
        float4 X1 = *(const float4*)&s_xw[c * XWS + x0 + 4];
        float gh0 = s_gh[c * GHS + 2 * ypr];
        float gh1 = s_gh[c * GHS + 2 * ypr + 1];
        float g0[8], g1[8];
        {
            float xwv[8] = {X0.x, X0.y, X0.z, X0.w, X1.x, X1.y, X1.z, X1.w};
            #pragma unroll
            for (int j = 0; j < 8; ++j) { g0[j] = gh0 * xwv[j]; g1[j] = gh1 * xwv[j]; }
        }

        float acc0[8], acc1[8];
        #pragma unroll
        for (int j = 0; j < 8; ++j) { acc0[j] = 0.f; acc1[j] = 0.f; }

        const int base = c * CSTR + 2 * ypr * LROW + x0;
        #pragma unroll
        for (int rr = 0; rr < 4; ++rr) {
            const float* rp = &s_in[base + rr * LROW];
            float4 R0 = *(const float4*)(rp);
            float4 R1 = *(const float4*)(rp + 4);
            float4 R2 = *(const float4*)(rp + 8);
            float4 R3 = *(const float4*)(rp + 12);
            float win[10] = {R0.w, R1.x, R1.y, R1.z, R1.w,
                             R2.x, R2.y, R2.z, R2.w, R3.x};
            if (rr < 3) {
                float a0 = w[3 * rr], a1 = w[3 * rr + 1], a2 = w[3 * rr + 2];
                #pragma unroll
                for (int j = 0; j < 8; ++j)
                    acc0[j] += a0 * win[j] + a1 * win[j + 1] + a2 * win[j + 2];
            }
            if (rr > 0) {
                float b0 = w[3 * (rr - 1)], b1 = w[3 * (rr - 1) + 1], b2 = w[3 * (rr - 1) + 2];
                #pragma unroll
                for (int j = 0; j < 8; ++j)
                    acc1[j] += b0 * win[j] + b1 * win[j + 1] + b2 * win[j + 2];
            }
            if (rr == 1) {
                #pragma unroll
                for (int j = 0; j < 8; ++j) acc0[j] += g0[j] * win[j + 1];
            }
            if (rr == 2) {
                #pragma unroll
                for (int j = 0; j < 8; ++j) acc1[j] += g1[j] * win[j + 1];
            }
        }

        // butterfly sum across the 16 channels (lanes differing in bits 0..3)
        #pragma unroll
        for (int m = 1; m <= 8; m <<= 1) {
            #pragma unroll
            for (int j = 0; j < 8; ++j) {
                acc0[j] += __shfl_xor(acc0[j], m);
                acc1[j] += __shfl_xor(acc1[j], m);
            }
        }

        float bias = s_bias;
        float sg0[8], sg1[8];
        #pragma unroll
        for (int j = 0; j < 8; ++j) {
            sg0[j] = 1.f / (1.f + __expf(-(acc0[j] + bias)));
            sg1[j] = 1.f / (1.f + __expf(-(acc1[j] + bias)));
        }

        // re-read this channel's center rows, multiply, store
        const float* c0p = &s_in[base + 1 * LROW + 4];
        const float* c1p = &s_in[base + 2 * LROW + 4];
        float4 C00 = *(const float4*)(c0p);
        float4 C01 = *(const float4*)(c0p + 4);
        float4 C10 = *(const float4*)(c1p);
        float4 C11 = *(const float4*)(c1p + 4);

        float* o0 = og + c * HW + (y0 + 2 * ypr) * WW + x0;
        float* o1 = o0 + WW;
        *(float4*)(o0)     = make_float4(C00.x * sg0[0], C00.y * sg0[1],
                                         C00.z * sg0[2], C00.w * sg0[3]);
        *(float4*)(o0 + 4) = make_float4(C01.x * sg0[4], C01.y * sg0[5],
                                         C01.z * sg0[6], C01.w * sg0[7]);
        *(float4*)(o1)     = make_float4(C10.x * sg1[0], C10.y * sg1[1],
                                         C10.z * sg1[2], C10.w * sg1[3]);
        *(float4*)(o1 + 4) = make_float4(C11.x * sg1[4], C11.y * sg1[5],
                                         C11.z * sg1[6], C11.w * sg1[7]);
    }
}

// ---------------------------------------------------------------------------
extern "C" void kernel_launch(void* const* d_in, const int* in_sizes, int n_in,
                              void* d_out, int out_size, void* d_ws, size_t ws_size,
                              hipStream_t stream)
{
    const float* x    = (const float*)d_in[0];
    const float* w1   = (const float*)d_in[1];
    const float* b1   = (const float*)d_in[2];
    const float* w3   = (const float*)d_in[3];
    const float* b3   = (const float*)d_in[4];
    const float* gn_w = (const float*)d_in[5];
    const float* gn_b = (const float*)d_in[6];
    float* out = (float*)d_out;

    float* ws = (float*)d_ws;
    float* ws_xh   = ws;                                    // BG*CG*HH
    float* ws_xw   = ws_xh + (size_t)BG * CG * HH;          // BG*CG*WW
    float* ws_asc  = ws_xw + (size_t)BG * CG * WW;          // BG*CG
    float* ws_aofs = ws_asc + (size_t)BG * CG;              // BG
    float* ws_wa   = ws_aofs + (size_t)BG;                  // CG*9 + 1

    kA<<<BG, 256, 0, stream>>>(x, w1, b1, w3, b3, gn_w, gn_b,
                               ws_xh, ws_xw, ws_asc, ws_aofs, ws_wa);
    kBC<<<BG * NB, 256, 0, stream>>>(x, ws_xh, ws_xw, ws_asc, ws_aofs,
                                     ws_wa, out);
}

// Round 6
// 476.795 us; speedup vs baseline: 1.0201x; 1.0201x over previous
//
#include <hip/hip_runtime.h>
#include <math.h>

#define GROUPS 32
#define CG 16
#define HH 56
#define WW 56
#define HW (HH*WW)          // 3136
#define BG 1024             // B*GROUPS
#define EPS 1e-5f

#define RB 4                // output rows per band
#define NB 14               // bands per instance (RB*NB == HH)
#define NR (RB+2)           // staged rows incl. halo = 6
#define LROW 60             // LDS row stride: [0..3] zero halo, [4..59] image
#define CPAD 4              // zero tail pad per channel (right-edge overread)
#define CSTR (NR*LROW+CPAD) // 364 floats/channel; 364%32=12 -> bank spread
#define XWS 60              // s_xw stride; 60%32=28 -> bank spread
#define XHS 57              // s_xh stride; odd -> full bank spread for gh reads

// phase-A scratch offsets inside s_u (all dead before the band loop)
#define U_ROW 0             // CG*HH = 896 row means
#define U_COL 896           // CG*WW = 896 col means
#define U_ST  1792          // CG*9  = 144 per-channel stats
#define U_X2P 1936          // CG*CG = 256 x2 partials [c][o]
#define U_LS1 2192          // 16 sum
#define U_LS2 2208          // 16 sumsq      (2224 <= CG*CSTR = 5824)

// ---------------------------------------------------------------------------
// kF: grand-fused per-instance kernel. One block per bg-instance.
//   A0: a1-folded conv weights (per block, LDS-only)
//   A1: directional pooling (pass 1 over gx, 2-row ILP shfl chains)
//   A2: 1x1 mix + sigmoid gates -> s_xh/s_xw (LDS only)
//   A3: per-channel stats for analytic x2sum
//   A4: x2 tap partials (256 threads)
//   A5: sum/sumsq of t = gx*xh*xw (pass 2 over gx)
//   A6: scale/shift + a2 softmax; fold asc into s_xh (gh); bias
//   BC: 14-band loop: stage 6 rows -> conv + channel butterfly + epilogue
// ---------------------------------------------------------------------------
__global__ __launch_bounds__(256, 4) void kF(const float* __restrict__ x,
        const float* __restrict__ w1, const float* __restrict__ b1,
        const float* __restrict__ w3, const float* __restrict__ b3,
        const float* __restrict__ gn_w, const float* __restrict__ gn_b,
        float* __restrict__ out)
{
    const int g = blockIdx.x;
    const int tid = threadIdx.x;
    const float* gx = x + (size_t)g * CG * HW;
    float* og = out + (size_t)g * CG * HW;

    __shared__ float s_u[CG * CSTR];    // 23296 B: scratch then band tile
    __shared__ float s_xh[CG * XHS];    // xh, becomes gh = asc*xh after A6
    __shared__ float s_xw[CG * XWS];    // xw (padded stride)
    __shared__ float s_wa[CG * 9 + 1];  // a1-folded weights + ab
    __shared__ float s_asc[CG];
    __shared__ float s_bias;

    // ---- A0: a1 = softmax(gn_b); wa[ci][k] = sum_o a1[o] w3[o][ci][k] ----
    if (tid < CG * 9 + 1) {
        float m = gn_b[0];
        #pragma unroll
        for (int c = 1; c < CG; ++c) m = fmaxf(m, gn_b[c]);
        float a1[CG]; float den = 0.f;
        #pragma unroll
        for (int c = 0; c < CG; ++c) { a1[c] = __expf(gn_b[c] - m); den += a1[c]; }
        float inv = 1.f / den;
        if (tid < CG * 9) {
            int ci = tid / 9, k = tid - (tid / 9) * 9;
            float s = 0.f;
            #pragma unroll
            for (int o = 0; o < CG; ++o) s += a1[o] * w3[(size_t)(o * CG + ci) * 9 + k];
            s_wa[tid] = s * inv;
        } else {
            float s = 0.f;
            #pragma unroll
            for (int o = 0; o < CG; ++o) s += a1[o] * b3[o];
            s_wa[CG * 9] = s * inv;
        }
    }

    // ---- A1: pooling, 16-lane group per channel, 2-row ILP ----
    {
        const int grp = tid >> 4;
        const int q   = tid & 15;
        const float* pc = gx + grp * HW;
        float c0 = 0.f, c1 = 0.f, c2 = 0.f, c3 = 0.f;
        #pragma unroll 2
        for (int row = 0; row < HH; row += 2) {
            float4 va = make_float4(0.f, 0.f, 0.f, 0.f);
            float4 vb = va;
            if (q < 14) {
                va = *(const float4*)(pc + row * WW + q * 4);
                vb = *(const float4*)(pc + (row + 1) * WW + q * 4);
            }
            c0 += va.x + vb.x; c1 += va.y + vb.y;
            c2 += va.z + vb.z; c3 += va.w + vb.w;
            float ra = (va.x + va.y) + (va.z + va.w);
            float rb = (vb.x + vb.y) + (vb.z + vb.w);
            ra += __shfl_down(ra, 8);  rb += __shfl_down(rb, 8);
            ra += __shfl_down(ra, 4);  rb += __shfl_down(rb, 4);
            ra += __shfl_down(ra, 2);  rb += __shfl_down(rb, 2);
            ra += __shfl_down(ra, 1);  rb += __shfl_down(rb, 1);
            if (q == 0) {
                s_u[U_ROW + grp * HH + row]     = ra * (1.0f / WW);
                s_u[U_ROW + grp * HH + row + 1] = rb * (1.0f / WW);
            }
        }
        if (q < 14) {
            s_u[U_COL + grp * WW + q * 4 + 0] = c0 * (1.0f / HH);
            s_u[U_COL + grp * WW + q * 4 + 1] = c1 * (1.0f / HH);
            s_u[U_COL + grp * WW + q * 4 + 2] = c2 * (1.0f / HH);
            s_u[U_COL + grp * WW + q * 4 + 3] = c3 * (1.0f / HH);
        }
    }
    __syncthreads();   // S1

    // ---- A2: 1x1 channel mix + bias + sigmoid -> s_xh, s_xw ----
    for (int t = tid; t < 2 * CG * HH; t += 256) {
        int hpart = (t < CG * HH);
        int tt = hpart ? t : t - CG * HH;
        int o = tt / HH, i = tt - (tt / HH) * HH;
        float v = b1[o];
        #pragma unroll
        for (int c = 0; c < CG; ++c)
            v += w1[o * CG + c] * (hpart ? s_u[U_ROW + c * HH + i]
                                         : s_u[U_COL + c * WW + i]);
        float sg = 1.f / (1.f + __expf(-v));
        if (hpart) s_xh[o * XHS + i] = sg;
        else       s_xw[o * XWS + i] = sg;
    }

    // ---- A3: per-channel stats for analytic x2sum (threads 0..15) ----
    if (tid < CG) {
        const int c = tid;
        float S = 0.f;
        #pragma unroll
        for (int r = 0; r < HH; ++r) S += s_u[U_ROW + c * HH + r];
        float* st = &s_u[U_ST + c * 9];
        st[0] = S * (float)WW;
        st[1] = (float)WW * s_u[U_ROW + c * HH + HH - 1];
        st[2] = (float)WW * s_u[U_ROW + c * HH];
        st[3] = (float)HH * s_u[U_COL + c * WW + WW - 1];
        st[4] = (float)HH * s_u[U_COL + c * WW];
        const float* p = gx + c * HW;
        st[5] = p[0];
        st[6] = p[WW - 1];
        st[7] = p[(HH - 1) * WW];
        st[8] = p[(HH - 1) * WW + WW - 1];
    }
    __syncthreads();   // S2

    // ---- A4: x2 tap partials, thread (o = tid>>4, c = tid&15) ----
    {
        const int o = tid >> 4, c = tid & 15;
        const float* wp = w3 + (size_t)(o * CG + c) * 9;
        const float* st = &s_u[U_ST + c * 9];
        float S = st[0];
        float acc = 0.f;
        #pragma unroll
        for (int dy = 0; dy < 3; ++dy) {
            float Rv = (dy == 0) ? st[1] : (dy == 2 ? st[2] : 0.f);
            #pragma unroll
            for (int dx = 0; dx < 3; ++dx) {
                float Cv = (dx == 0) ? st[3] : (dx == 2 ? st[4] : 0.f);
                float T = S - Rv - Cv;
                if (dy != 1 && dx != 1)
                    T += (dy == 0) ? ((dx == 0) ? st[8] : st[7])
                                   : ((dx == 0) ? st[6] : st[5]);
                acc += wp[dy * 3 + dx] * T;
            }
        }
        s_u[U_X2P + c * CG + o] = acc;
    }

    // ---- A5: sum/sumsq of t = gx*xh*xw (pass 2), 16-lane group/channel ----
    {
        const int c = tid >> 4;
        const int q = tid & 15;
        float s1 = 0.f, s2 = 0.f;
        if (q < 14) {
            const float* pc = gx + c * HW;
            float xw0 = s_xw[c * XWS + q * 4 + 0], xw1 = s_xw[c * XWS + q * 4 + 1];
            float xw2 = s_xw[c * XWS + q * 4 + 2], xw3v = s_xw[c * XWS + q * 4 + 3];
            #pragma unroll 4
            for (int row = 0; row < HH; ++row) {
                float4 v = *(const float4*)(pc + row * WW + q * 4);
                float xh = s_xh[c * XHS + row];
                float t0 = v.x * xh * xw0;
                float t1 = v.y * xh * xw1;
                float t2 = v.z * xh * xw2;
                float t3 = v.w * xh * xw3v;
                s1 += (t0 + t1) + (t2 + t3);
                s2 += (t0 * t0 + t1 * t1) + (t2 * t2 + t3 * t3);
            }
        }
        s1 += __shfl_down(s1, 8);  s2 += __shfl_down(s2, 8);
        s1 += __shfl_down(s1, 4);  s2 += __shfl_down(s2, 4);
        s1 += __shfl_down(s1, 2);  s2 += __shfl_down(s2, 2);
        s1 += __shfl_down(s1, 1);  s2 += __shfl_down(s2, 1);
        if (q == 0) { s_u[U_LS1 + c] = s1; s_u[U_LS2 + c] = s2; }
    }
    __syncthreads();   // S3

    // ---- A6a (threads 0..15): scale/shift, a2 softmax, asc, bias ----
    if (tid < CG) {
        const int o = tid;
        float x2 = (float)HW * b3[o];
        #pragma unroll
        for (int c = 0; c < CG; ++c) x2 += s_u[U_X2P + c * CG + o];

        float mu  = s_u[U_LS1 + o] * (1.0f / HW);
        float var = s_u[U_LS2 + o] * (1.0f / HW) - mu * mu;
        float sc  = gn_w[o] * rsqrtf(var + EPS);
        float sh  = gn_b[o] - mu * sc;

        float v2 = x2 * (1.0f / HW);
        float m = v2;
        #pragma unroll
        for (int off = 8; off; off >>= 1) m = fmaxf(m, __shfl_xor(m, off));
        float e = __expf(v2 - m);
        float den = e;
        #pragma unroll
        for (int off = 8; off; off >>= 1) den += __shfl_xor(den, off);
        float a2 = e / den;

        s_asc[o] = a2 * sc;
        float part = a2 * sh;
        #pragma unroll
        for (int off = 8; off; off >>= 1) part += __shfl_xor(part, off);
        if (o == 0) s_bias = part + s_wa[CG * 9];
    }
    __syncthreads();   // S4

    // ---- A6b: fold asc into s_xh (gh) + zero band-tile halos ----
    if (tid < 96) {                       // left halo cols [0..3] per (c,row)
        int c = tid / NR, r = tid - (tid / NR) * NR;
        *(float4*)&s_u[c * CSTR + r * LROW] = make_float4(0.f, 0.f, 0.f, 0.f);
    } else if (tid < 112) {               // channel tail pad [360..363]
        int c = tid - 96;
        *(float4*)&s_u[c * CSTR + NR * LROW] = make_float4(0.f, 0.f, 0.f, 0.f);
    }
    for (int t = tid; t < CG * HH; t += 256) {
        int c = t / HH, y = t - (t / HH) * HH;
        s_xh[c * XHS + y] *= s_asc[c];
    }
    // (no barrier needed here: band-0's post-stage barrier covers these writes)

    // ---- BC: hoisted per-thread conv constants ----
    int cc = 0, ypr = 0, x0 = 0;
    float wreg[9];
    float xwv[8];
    if (tid < 224) {
        cc  = tid & 15;
        int sp = tid >> 4;
        ypr = sp / 7;
        x0  = (sp - ypr * 7) * 8;
        #pragma unroll
        for (int i = 0; i < 9; ++i) wreg[i] = s_wa[cc * 9 + i];
        float4 X0 = *(const float4*)&s_xw[cc * XWS + x0];
        float4 X1 = *(const float4*)&s_xw[cc * XWS + x0 + 4];
        xwv[0] = X0.x; xwv[1] = X0.y; xwv[2] = X0.z; xwv[3] = X0.w;
        xwv[4] = X1.x; xwv[5] = X1.y; xwv[6] = X1.z; xwv[7] = X1.w;
    }

    // ---- BC: 14-band loop ----
    for (int band = 0; band < NB; ++band) {
        const int y0 = band * RB;

        // stage rows y0-1 .. y0+RB (zeros for out-of-image rows)
        for (int t = tid; t < CG * NR * 14; t += 256) {   // 1344
            int c = t / (NR * 14);
            int rem = t - c * (NR * 14);
            int r = rem / 14, q = rem - r * 14;
            int ry = y0 - 1 + r;
            float4 v = make_float4(0.f, 0.f, 0.f, 0.f);
            if (ry >= 0 && ry < HH)
                v = *(const float4*)(gx + c * HW + ry * WW + 4 * q);
            *(float4*)&s_u[c * CSTR + r * LROW + 4 + 4 * q] = v;
        }
        __syncthreads();

        if (tid < 224) {
            float gh0 = s_xh[cc * XHS + y0 + 2 * ypr];
            float gh1 = s_xh[cc * XHS + y0 + 2 * ypr + 1];
            float g0[8], g1[8];
            #pragma unroll
            for (int j = 0; j < 8; ++j) { g0[j] = gh0 * xwv[j]; g1[j] = gh1 * xwv[j]; }

            float acc0[8], acc1[8];
            #pragma unroll
            for (int j = 0; j < 8; ++j) { acc0[j] = 0.f; acc1[j] = 0.f; }

            const int base = cc * CSTR + 2 * ypr * LROW + x0;
            #pragma unroll
            for (int rr = 0; rr < 4; ++rr) {
                const float* rp = &s_u[base + rr * LROW];
                float4 R0 = *(const float4*)(rp);
                float4 R1 = *(const float4*)(rp + 4);
                float4 R2 = *(const float4*)(rp + 8);
                float4 R3 = *(const float4*)(rp + 12);
                float win[10] = {R0.w, R1.x, R1.y, R1.z, R1.w,
                                 R2.x, R2.y, R2.z, R2.w, R3.x};
                if (rr < 3) {
                    float a0 = wreg[3 * rr], a1 = wreg[3 * rr + 1], a2 = wreg[3 * rr + 2];
                    #pragma unroll
                    for (int j = 0; j < 8; ++j)
                        acc0[j] += a0 * win[j] + a1 * win[j + 1] + a2 * win[j + 2];
                }
                if (rr > 0) {
                    float b0 = wreg[3 * (rr - 1)], b1v = wreg[3 * (rr - 1) + 1],
                          b2 = wreg[3 * (rr - 1) + 2];
                    #pragma unroll
                    for (int j = 0; j < 8; ++j)
                        acc1[j] += b0 * win[j] + b1v * win[j + 1] + b2 * win[j + 2];
                }
                if (rr == 1) {
                    #pragma unroll
                    for (int j = 0; j < 8; ++j) acc0[j] += g0[j] * win[j + 1];
                }
                if (rr == 2) {
                    #pragma unroll
                    for (int j = 0; j < 8; ++j) acc1[j] += g1[j] * win[j + 1];
                }
            }

            // butterfly sum across the 16 channels
            #pragma unroll
            for (int m = 1; m <= 8; m <<= 1) {
                #pragma unroll
                for (int j = 0; j < 8; ++j) {
                    acc0[j] += __shfl_xor(acc0[j], m);
                    acc1[j] += __shfl_xor(acc1[j], m);
                }
            }

            float bias = s_bias;
            float sg0[8], sg1[8];
            #pragma unroll
            for (int j = 0; j < 8; ++j) {
                sg0[j] = 1.f / (1.f + __expf(-(acc0[j] + bias)));
                sg1[j] = 1.f / (1.f + __expf(-(acc1[j] + bias)));
            }

            const float* c0p = &s_u[base + 1 * LROW + 4];
            const float* c1p = &s_u[base + 2 * LROW + 4];
            float4 C00 = *(const float4*)(c0p);
            float4 C01 = *(const float4*)(c0p + 4);
            float4 C10 = *(const float4*)(c1p);
            float4 C11 = *(const float4*)(c1p + 4);

            float* o0 = og + cc * HW + (y0 + 2 * ypr) * WW + x0;
            float* o1 = o0 + WW;
            *(float4*)(o0)     = make_float4(C00.x * sg0[0], C00.y * sg0[1],
                                             C00.z * sg0[2], C00.w * sg0[3]);
            *(float4*)(o0 + 4) = make_float4(C01.x * sg0[4], C01.y * sg0[5],
                                             C01.z * sg0[6], C01.w * sg0[7]);
            *(float4*)(o1)     = make_float4(C10.x * sg1[0], C10.y * sg1[1],
                                             C10.z * sg1[2], C10.w * sg1[3]);
            *(float4*)(o1 + 4) = make_float4(C11.x * sg1[4], C11.y * sg1[5],
                                             C11.z * sg1[6], C11.w * sg1[7]);
        }
        __syncthreads();   // protect s_u before next band's staging
    }
}

// ---------------------------------------------------------------------------
extern "C" void kernel_launch(void* const* d_in, const int* in_sizes, int n_in,
                              void* d_out, int out_size, void* d_ws, size_t ws_size,
                              hipStream_t stream)
{
    const float* x    = (const float*)d_in[0];
    const float* w1   = (const float*)d_in[1];
    const float* b1   = (const float*)d_in[2];
    const float* w3   = (const float*)d_in[3];
    const float* b3   = (const float*)d_in[4];
    const float* gn_w = (const float*)d_in[5];
    const float* gn_b = (const float*)d_in[6];
    float* out = (float*)d_out;
    (void)d_ws; (void)ws_size;

    kF<<<BG, 256, 0, stream>>>(x, w1, b1, w3, b3, gn_w, gn_b, out);
}